// Round 7
// baseline (85.299 us; speedup 1.0000x reference)
//
#include <hip/hip_runtime.h>

// Problem constants (match reference)
#define S_AR 3072
#define NH 16
#define NB 4
#define ND 128
#define NTOT (S_AR * NH * NB * ND)   // 25,165,824 elems per tensor
#define N4   (NTOT / 4)              // 6,291,456 float4 per tensor
#define TPB 256
#define HALF_BLOCKS 2048             // blocks per tensor
#define STRIDE (HALF_BLOCKS * TPB)   // 524,288 threads per tensor (2^19)
#define ITERS (N4 / STRIDE)          // exactly 12, no remainder

// Native clang vector type — required by __builtin_nontemporal_{load,store}
typedef float vf4 __attribute__((ext_vector_type(4)));

__device__ __forceinline__ float max4abs(vf4 a) {
    return fmaxf(fmaxf(fabsf(a.x), fabsf(a.y)), fmaxf(fabsf(a.z), fabsf(a.w)));
}

// K/V-split streaming dequant with a BRANCH-FREE hot loop.
// The special row s==idx covers float4 indices [idx*2048, idx*2048+2048):
// a block-aligned 2048-thread span hit in exactly iteration it0 = idx>>8.
// Those 8 blocks precompute the quantized override in a uniform cold pre-pass;
// the hot loop is pure NT-load -> mul -> select -> NT-store straight-line code.
__global__ void __launch_bounds__(TPB) kv_dequant_split(
    const vf4* __restrict__ key4, const vf4* __restrict__ val4,
    const vf4* __restrict__ ck,   const vf4* __restrict__ cv,
    const float* __restrict__ ksc, const float* __restrict__ vsc,
    const int* __restrict__ idxp,
    vf4* __restrict__ ok, vf4* __restrict__ ov)
{
    const float inv = 1.0f / 127.5f;
    const int idx  = *idxp;                       // uniform scalar load
    const int half = blockIdx.x >> 11;            // 0 = K, 1 = V
    const int tid  = (blockIdx.x & (HALF_BLOCKS - 1)) * TPB + threadIdx.x;

    const vf4*   src  = half ? cv   : ck;
    const float* sc   = half ? vsc  : ksc;
    const vf4*   new4 = half ? val4 : key4;
    vf4*         dst  = half ? ov   : ok;

    // ---- cold pre-pass: compute override for the special row (8 blocks) ----
    int sp_it = -1;                               // iteration to override (-1: none)
    vf4 ovr = {0.f, 0.f, 0.f, 0.f};
    {
        const int r = (idx & 255) << 11;          // span start within STRIDE
        if (tid >= r && tid < r + 2048) {         // block-uniform condition
            const int it0 = idx >> 8;
            const int i   = tid + it0 * STRIDE;   // global float4 index, s==idx
            const int row = i >> 5;               // (s,h,b) flat row
            const int h = (row >> 2) & 15;
            const int b = row & 3;
            const vf4 n = new4[(b * NH + h) * (ND / 4) + (i & 31)];
            float m = max4abs(n);
            #pragma unroll
            for (int o = 16; o; o >>= 1)          // stays within 32-lane group
                m = fmaxf(m, __shfl_xor(m, o));
            const float q = 127.5f / m, d = m * inv;
            ovr.x = rintf(n.x * q) * d; ovr.y = rintf(n.y * q) * d;
            ovr.z = rintf(n.z * q) * d; ovr.w = rintf(n.w * q) * d;
            sp_it = it0;
        }
    }

    // ---- hot loop: branch-free streaming ----
    #pragma unroll
    for (int it = 0; it < ITERS; ++it) {
        const int i = tid + it * STRIDE;
        vf4 x = __builtin_nontemporal_load(&src[i]);
        x *= sc[i >> 5] * inv;
        x = (it == sp_it) ? ovr : x;              // scalar cmp + v_cndmask x4
        __builtin_nontemporal_store(x, &dst[i]);
    }
}

extern "C" void kernel_launch(void* const* d_in, const int* in_sizes, int n_in,
                              void* d_out, int out_size, void* d_ws, size_t ws_size,
                              hipStream_t stream) {
    const float* key   = (const float*)d_in[0];
    const float* value = (const float*)d_in[1];
    const float* ck    = (const float*)d_in[2];
    const float* cv    = (const float*)d_in[3];
    const float* ksc   = (const float*)d_in[4];
    const float* vsc   = (const float*)d_in[5];
    const int*   idxp  = (const int*)d_in[6];

    float* out_k = (float*)d_out;
    float* out_v = (float*)d_out + NTOT;

    kv_dequant_split<<<dim3(2 * HALF_BLOCKS), dim3(TPB), 0, stream>>>(
        (const vf4*)key, (const vf4*)value,
        (const vf4*)ck, (const vf4*)cv,
        ksc, vsc, idxp,
        (vf4*)out_k, (vf4*)out_v);
}

// Round 8
// 72.296 us; speedup vs baseline: 1.1799x; 1.1799x over previous
//
#include <hip/hip_runtime.h>

// Problem constants (match reference)
#define S_AR 3072
#define NH 16
#define NB 4
#define ND 128
#define NTOT (S_AR * NH * NB * ND)   // 25,165,824 elems per tensor
#define N4   (NTOT / 4)              // 6,291,456 float4 per tensor
#define TPB 256
#define HALF_BLOCKS 1024             // blocks per tensor (2048 total = 8/CU, all-resident)
#define STRIDE (HALF_BLOCKS * TPB)   // 262,144 threads per tensor (2^18)
#define ITERS (N4 / STRIDE)          // exactly 24, no remainder

// Native clang vector type — required by __builtin_nontemporal_{load,store}
typedef float vf4 __attribute__((ext_vector_type(4)));

__device__ __forceinline__ float max4abs(vf4 a) {
    return fmaxf(fmaxf(fabsf(a.x), fabsf(a.y)), fmaxf(fabsf(a.z), fabsf(a.w)));
}

// K/V-split streaming dequant, 16 B/lane contiguous, exactly-resident grid:
// 2048 blocks x 4 waves = 8192 waves = one full scheduling generation
// (no second-generation tail). Blocks [0,HALF_BLOCKS) stream K, rest V.
// Hot path branchy-cold (R4 structure — beat both branch-free and prefetch
// restructurings). One (s,h,b) row = 32 float4 = one aligned 32-lane group.
__global__ void __launch_bounds__(TPB, 8) kv_dequant_split(
    const vf4* __restrict__ key4, const vf4* __restrict__ val4,
    const vf4* __restrict__ ck,   const vf4* __restrict__ cv,
    const float* __restrict__ ksc, const float* __restrict__ vsc,
    const int* __restrict__ idxp,
    vf4* __restrict__ ok, vf4* __restrict__ ov)
{
    const float inv = 1.0f / 127.5f;
    const int idx  = *idxp;                       // uniform scalar load
    const int half = blockIdx.x >> 10;            // 0 = K, 1 = V
    const int tid  = (blockIdx.x & (HALF_BLOCKS - 1)) * TPB + threadIdx.x;

    const vf4*   src  = half ? cv   : ck;
    const float* sc   = half ? vsc  : ksc;
    const vf4*   new4 = half ? val4 : key4;
    vf4*         dst  = half ? ov   : ok;

    #pragma unroll
    for (int it = 0; it < ITERS; ++it) {
        const int i   = tid + it * STRIDE;
        const int row = i >> 5;                   // (s,h,b) flat row
        vf4 x = __builtin_nontemporal_load(&src[i]);
        x *= sc[row] * inv;
        if (__builtin_expect((row >> 6) == idx, 0)) {   // s == idx : new step
            const int h = (row >> 2) & 15;
            const int b = row & 3;
            const vf4 n = new4[(b * NH + h) * (ND / 4) + (i & 31)];
            float m = max4abs(n);
            #pragma unroll
            for (int o = 16; o; o >>= 1)          // stays within 32-lane group
                m = fmaxf(m, __shfl_xor(m, o));
            const float q = 127.5f / m, d = m * inv;
            x.x = rintf(n.x * q) * d; x.y = rintf(n.y * q) * d;
            x.z = rintf(n.z * q) * d; x.w = rintf(n.w * q) * d;
        }
        __builtin_nontemporal_store(x, &dst[i]);
    }
}

extern "C" void kernel_launch(void* const* d_in, const int* in_sizes, int n_in,
                              void* d_out, int out_size, void* d_ws, size_t ws_size,
                              hipStream_t stream) {
    const float* key   = (const float*)d_in[0];
    const float* value = (const float*)d_in[1];
    const float* ck    = (const float*)d_in[2];
    const float* cv    = (const float*)d_in[3];
    const float* ksc   = (const float*)d_in[4];
    const float* vsc   = (const float*)d_in[5];
    const int*   idxp  = (const int*)d_in[6];

    float* out_k = (float*)d_out;
    float* out_v = (float*)d_out + NTOT;

    kv_dequant_split<<<dim3(2 * HALF_BLOCKS), dim3(TPB), 0, stream>>>(
        (const vf4*)key, (const vf4*)value,
        (const vf4*)ck, (const vf4*)cv,
        ksc, vsc, idxp,
        (vf4*)out_k, (vf4*)out_v);
}